// Round 1
// baseline (10230.979 us; speedup 1.0000x reference)
//
#include <hip/hip_runtime.h>
#include <math.h>

#define Bc   2
#define Lc   2048
#define Hc   1024
#define NHc  16
#define Dc   64
#define Mc   (Bc*Lc)     // 4096
#define H6   (6*Hc)      // 6144
#define QKVN (3*Hc)      // 3072
#define MLPH 2816

__device__ __forceinline__ float wave_reduce_sum(float v) {
    #pragma unroll
    for (int m = 1; m < 64; m <<= 1) v += __shfl_xor(v, m, 64);
    return v;
}
__device__ __forceinline__ float wave_reduce_max(float v) {
    #pragma unroll
    for (int m = 1; m < 64; m <<= 1) v = fmaxf(v, __shfl_xor(v, m, 64));
    return v;
}

// ---------------- mod = silu(cond) @ mod_w.T + mod_b ----------------
__global__ void mod_kernel(const float* __restrict__ cond, const float* __restrict__ mw,
                           const float* __restrict__ mb, float* __restrict__ mod) {
    __shared__ float sc[Hc];
    int b = blockIdx.y;
    int tid = threadIdx.x;
    for (int i = tid; i < Hc; i += 256) {
        float c = cond[b*Hc + i];
        sc[i] = c / (1.f + __expf(-c));
    }
    __syncthreads();
    int j = blockIdx.x*256 + tid;
    const float* wr = mw + (size_t)j*Hc;
    float acc = 0.f;
    #pragma unroll 8
    for (int i = 0; i < Hc; ++i) acc += sc[i]*wr[i];
    mod[b*H6 + j] = acc + mb[j];
}

// ---------------- out = layernorm(x)*(1+scale)+shift ----------------
__global__ void ln_mod_kernel(const float* __restrict__ x, const float* __restrict__ mod,
                              int shift_off, int scale_off, float* __restrict__ out) {
    int m = blockIdx.x;
    int b = m >> 11;            // m / Lc
    int tid = threadIdx.x;
    const float4* xr = (const float4*)(x + (size_t)m*Hc);
    float4 v = xr[tid];         // 256 threads * 4 floats = 1024
    float s1 = v.x+v.y+v.z+v.w;
    float s2 = v.x*v.x + v.y*v.y + v.z*v.z + v.w*v.w;
    s1 = wave_reduce_sum(s1); s2 = wave_reduce_sum(s2);
    __shared__ float red[8];
    int wid = tid >> 6, lane = tid & 63;
    if (lane == 0) { red[wid] = s1; red[4+wid] = s2; }
    __syncthreads();
    s1 = red[0]+red[1]+red[2]+red[3];
    s2 = red[4]+red[5]+red[6]+red[7];
    float mean = s1 * (1.f/Hc);
    float var  = s2 * (1.f/Hc) - mean*mean;
    float inv  = rsqrtf(var + 1e-5f);
    const float4* sh = (const float4*)(mod + b*H6 + shift_off);
    const float4* sc = (const float4*)(mod + b*H6 + scale_off);
    float4 shv = sh[tid], scv = sc[tid];
    float4 o;
    o.x = (v.x-mean)*inv*(1.f+scv.x)+shv.x;
    o.y = (v.y-mean)*inv*(1.f+scv.y)+shv.y;
    o.z = (v.z-mean)*inv*(1.f+scv.z)+shv.z;
    o.w = (v.w-mean)*inv*(1.f+scv.w)+shv.w;
    ((float4*)(out + (size_t)m*Hc))[tid] = o;
}

// ---------------- generic tiled GEMM / conv1d(k=3) ----------------
// C[M,N] = sum_t shift(A,t-1)[M,K] * W[N,K,TAPS] (+bias) ; epilogues:
//   DUAL:   C = silu(acc1) * acc2   (two weight tensors)
//   gated:  C = prev + gate[b][n]*(acc+bias)
template<int TAPS, bool DUAL, int N, int K>
__global__ void gemm_kernel(const float* __restrict__ A,
                            const float* __restrict__ W1,
                            const float* __restrict__ W2,
                            const float* __restrict__ bias,
                            const float* __restrict__ prev,
                            const float* __restrict__ mod, int gate_off,
                            float* __restrict__ C) {
    __shared__ float As[16][68];
    __shared__ float Bs[16][68];
    __shared__ float Bs2[DUAL ? 16 : 1][68];
    int tid = threadIdx.x;
    int tx = tid & 15, ty = tid >> 4;
    int m0 = blockIdx.y * 64, n0 = blockIdx.x * 64;
    float acc[4][4] = {};
    float acc2[4][4] = {};
    int tk = tid & 15;     // k-col within tile
    int tr = tid >> 4;     // row group

    for (int t = 0; t < TAPS; ++t) {
        const int sh = (TAPS == 3) ? (t - 1) : 0;
        for (int k0 = 0; k0 < K; k0 += 16) {
            #pragma unroll
            for (int r = 0; r < 64; r += 16) {
                int gm = m0 + tr + r;
                int l  = gm & (Lc-1);
                int sl = l + sh;
                float v = 0.f;
                if (sl >= 0 && sl < Lc)
                    v = A[(size_t)(gm + sh)*K + k0 + tk];
                As[tk][tr + r] = v;
            }
            #pragma unroll
            for (int r = 0; r < 64; r += 16) {
                int gn = n0 + tr + r;
                size_t widx = ((size_t)gn*K + k0 + tk)*TAPS + t;
                Bs[tk][tr + r] = W1[widx];
                if (DUAL) Bs2[tk][tr + r] = W2[widx];
            }
            __syncthreads();
            #pragma unroll
            for (int kk = 0; kk < 16; ++kk) {
                float4 a  = *(const float4*)&As[kk][ty*4];
                float4 b1 = *(const float4*)&Bs[kk][tx*4];
                float av[4] = {a.x, a.y, a.z, a.w};
                float bv[4] = {b1.x, b1.y, b1.z, b1.w};
                #pragma unroll
                for (int i = 0; i < 4; ++i)
                    #pragma unroll
                    for (int j = 0; j < 4; ++j)
                        acc[i][j] += av[i]*bv[j];
                if (DUAL) {
                    float4 b2 = *(const float4*)&Bs2[kk][tx*4];
                    float b2v[4] = {b2.x, b2.y, b2.z, b2.w};
                    #pragma unroll
                    for (int i = 0; i < 4; ++i)
                        #pragma unroll
                        for (int j = 0; j < 4; ++j)
                            acc2[i][j] += av[i]*b2v[j];
                }
            }
            __syncthreads();
        }
    }
    #pragma unroll
    for (int i = 0; i < 4; ++i) {
        int gm = m0 + ty*4 + i;
        int b  = gm >> 11;
        #pragma unroll
        for (int j = 0; j < 4; ++j) {
            int gn = n0 + tx*4 + j;
            float r = acc[i][j];
            if (DUAL) {
                r = r / (1.f + __expf(-r)) * acc2[i][j];
            } else {
                if (bias) r += bias[gn];
                if (mod)  r = prev[(size_t)gm*N + gn] + mod[b*H6 + gate_off + gn] * r;
            }
            C[(size_t)gm*N + gn] = r;
        }
    }
}

// ---------------- RMSNorm + RoPE + split qkv ----------------
__global__ void rope_rms_kernel(const float* __restrict__ qkv,
                                const float* __restrict__ qn_w, const float* __restrict__ kn_w,
                                const float* __restrict__ fcos, const float* __restrict__ fsin,
                                float* __restrict__ Q, float* __restrict__ K, float* __restrict__ V) {
    int bh = blockIdx.y;                      // b*NH + h
    int l  = blockIdx.x*4 + (threadIdx.x >> 6);
    int d  = threadIdx.x & 63;
    int b  = bh >> 4, h = bh & 15;
    size_t base = ((size_t)(b*Lc + l))*QKVN + (size_t)(h*Dc + d)*3;
    float qv = qkv[base + 0];
    float kv = qkv[base + 1];
    float vv = qkv[base + 2];
    float qs = wave_reduce_sum(qv*qv) * (1.f/Dc);
    float ks = wave_reduce_sum(kv*kv) * (1.f/Dc);
    float qn = qv * rsqrtf(qs + 1e-6f) * qn_w[d];
    float kn = kv * rsqrtf(ks + 1e-6f) * kn_w[d];
    float c = fcos[l*Dc + d], s = fsin[l*Dc + d];
    float qp = __shfl_xor(qn, 1, 64);
    float kp = __shfl_xor(kn, 1, 64);
    float qr = (d & 1) ? qp : -qp;
    float kr = (d & 1) ? kp : -kp;
    size_t o = ((size_t)bh*Lc + l)*Dc + d;
    Q[o] = qn*c + qr*s;
    K[o] = kn*c + kr*s;
    V[o] = vv;
}

// ---------------- attention: one block per (b,h,query-row) ----------------
__global__ void attn_kernel(const float* __restrict__ Q, const float* __restrict__ K,
                            const float* __restrict__ V, float* __restrict__ O) {
    __shared__ float s[Lc];
    __shared__ float sq[Dc];
    __shared__ float red[8];
    __shared__ float pacc[4][Dc];
    int lq = blockIdx.x, bh = blockIdx.y;
    int tid = threadIdx.x;
    if (tid < Dc) sq[tid] = Q[((size_t)bh*Lc + lq)*Dc + tid];
    __syncthreads();
    float4 q4[16];
    const float4* sq4 = (const float4*)sq;
    #pragma unroll
    for (int i = 0; i < 16; ++i) q4[i] = sq4[i];
    const float4* Kb4 = (const float4*)(K + (size_t)bh*Lc*Dc);
    for (int j = tid; j < Lc; j += 256) {
        const float4* kr = Kb4 + (size_t)j*16;
        float acc = 0.f;
        #pragma unroll
        for (int i = 0; i < 16; ++i) {
            float4 kv = kr[i];
            acc += q4[i].x*kv.x + q4[i].y*kv.y + q4[i].z*kv.z + q4[i].w*kv.w;
        }
        s[j] = acc * 0.125f;   // 1/sqrt(64)
    }
    __syncthreads();
    float mx = -1e30f;
    for (int j = tid; j < Lc; j += 256) mx = fmaxf(mx, s[j]);
    mx = wave_reduce_max(mx);
    int wid = tid >> 6, lane = tid & 63;
    if (lane == 0) red[wid] = mx;
    __syncthreads();
    mx = fmaxf(fmaxf(red[0], red[1]), fmaxf(red[2], red[3]));
    float sum = 0.f;
    for (int j = tid; j < Lc; j += 256) { float p = __expf(s[j]-mx); s[j] = p; sum += p; }
    sum = wave_reduce_sum(sum);
    if (lane == 0) red[4+wid] = sum;
    __syncthreads();
    sum = red[4]+red[5]+red[6]+red[7];
    float inv = 1.f/sum;
    int d = tid & 63, c = tid >> 6;
    const float* Vb = V + (size_t)bh*Lc*Dc;
    float acc = 0.f;
    for (int j = c*(Lc/4); j < (c+1)*(Lc/4); ++j)
        acc += s[j] * Vb[(size_t)j*Dc + d];
    pacc[c][d] = acc;
    __syncthreads();
    if (tid < Dc) {
        float o = (pacc[0][d]+pacc[1][d]+pacc[2][d]+pacc[3][d]) * inv;
        int b = bh >> 4, h = bh & 15;
        O[((size_t)(b*Lc + lq))*Hc + (size_t)h*Dc + d] = o;
    }
}

extern "C" void kernel_launch(void* const* d_in, const int* in_sizes, int n_in,
                              void* d_out, int out_size, void* d_ws, size_t ws_size,
                              hipStream_t stream) {
    const float* x      = (const float*)d_in[0];
    const float* cond   = (const float*)d_in[1];
    const float* fcos   = (const float*)d_in[2];
    const float* fsin   = (const float*)d_in[3];
    const float* mod_w  = (const float*)d_in[4];
    const float* mod_b  = (const float*)d_in[5];
    const float* qkv_w  = (const float*)d_in[6];
    const float* qkv_b  = (const float*)d_in[7];
    const float* qn_w   = (const float*)d_in[8];
    const float* kn_w   = (const float*)d_in[9];
    const float* lin1_w = (const float*)d_in[10];
    const float* lin1_b = (const float*)d_in[11];
    const float* w1     = (const float*)d_in[12];
    const float* w2     = (const float*)d_in[13];
    const float* w3     = (const float*)d_in[14];
    float* out = (float*)d_out;
    float* ws  = (float*)d_ws;

    float* mod = ws;                               // 16384 (12288 used)
    float* xn1 = mod + 16384;                      // Mc*Hc
    float* qkv = xn1 + (size_t)Mc*Hc;              // Mc*QKVN
    float* Qb  = qkv + (size_t)Mc*QKVN;            // Mc*Hc
    float* Kb  = Qb  + (size_t)Mc*Hc;              // Mc*Hc
    float* Vb  = Kb  + (size_t)Mc*Hc;              // Mc*Hc
    // aliases (lifetimes disjoint)
    float* attn = xn1;      // reuse after qkv GEMM consumed xn1
    float* xn2  = Qb;       // reuse after attention consumed Q
    float* h1   = qkv;      // reuse after attention (Mc*MLPH < Mc*QKVN)
    float* x1   = out;      // d_out doubles as residual buffer

    dim3 blk(256);
    // 1. modulation vector
    mod_kernel<<<dim3(H6/256, Bc), blk, 0, stream>>>(cond, mod_w, mod_b, mod);
    // 2. x_norm1
    ln_mod_kernel<<<Mc, blk, 0, stream>>>(x, mod, 0*Hc, 1*Hc, xn1);
    // 3. qkv = xn1 @ qkv_w.T + qkv_b
    gemm_kernel<1,false,QKVN,Hc><<<dim3(QKVN/64, Mc/64), blk, 0, stream>>>(
        xn1, qkv_w, nullptr, qkv_b, nullptr, nullptr, 0, qkv);
    // 4. RMSNorm + RoPE + split
    rope_rms_kernel<<<dim3(Lc/4, Bc*NHc), blk, 0, stream>>>(
        qkv, qn_w, kn_w, fcos, fsin, Qb, Kb, Vb);
    // 5. attention
    attn_kernel<<<dim3(Lc, Bc*NHc), blk, 0, stream>>>(Qb, Kb, Vb, attn);
    // 6. x1 = x + gate_msa * (conv1d(attn, lin1_w) + lin1_b)
    gemm_kernel<3,false,Hc,Hc><<<dim3(Hc/64, Mc/64), blk, 0, stream>>>(
        attn, lin1_w, nullptr, lin1_b, x, mod, 2*Hc, x1);
    // 7. x_norm2
    ln_mod_kernel<<<Mc, blk, 0, stream>>>(x1, mod, 3*Hc, 4*Hc, xn2);
    // 8. h1 = silu(conv1d(xn2,w1)) * conv1d(xn2,w3)
    gemm_kernel<3,true,MLPH,Hc><<<dim3(MLPH/64, Mc/64), blk, 0, stream>>>(
        xn2, w1, w3, nullptr, nullptr, nullptr, 0, h1);
    // 9. out = x1 + gate_mlp * conv1d(h1, w2)   (in-place on d_out)
    gemm_kernel<3,false,Hc,MLPH><<<dim3(Hc/64, Mc/64), blk, 0, stream>>>(
        h1, w2, nullptr, nullptr, x1, mod, 5*Hc, out);
}

// Round 2
// 688.502 us; speedup vs baseline: 14.8598x; 14.8598x over previous
//
#include <hip/hip_runtime.h>
#include <math.h>

typedef unsigned short u16;
typedef __attribute__((ext_vector_type(8))) short bf16x8;   // 8 bf16 (4 VGPRs)
typedef __attribute__((ext_vector_type(4))) float f32x4;

#define Bc   2
#define Lc   2048
#define Hc   1024
#define H6   6144
#define Mc   4096          // B*L
#define LPAD 2050          // padded rows per batch (1 zero row each side)

__device__ __forceinline__ u16 f2b(float f) {
    union { float f; unsigned u; } x; x.f = f;
    unsigned r = x.u + 0x7fffu + ((x.u >> 16) & 1u);
    return (u16)(r >> 16);
}
__device__ __forceinline__ float b2f(u16 h) {
    union { unsigned u; float f; } x; x.u = ((unsigned)h) << 16;
    return x.f;
}
__device__ __forceinline__ void async16(u16* lds, const u16* g) {
    __builtin_amdgcn_global_load_lds((const __attribute__((address_space(1))) void*)g,
                                     (__attribute__((address_space(3))) void*)lds, 16, 0, 0);
}
__device__ __forceinline__ float wave_reduce_sum(float v) {
    #pragma unroll
    for (int m = 1; m < 64; m <<= 1) v += __shfl_xor(v, m, 64);
    return v;
}

// ---------------- mod = silu(cond) @ mod_w.T + mod_b (f32, tiny) ----------------
__global__ void mod_kernel(const float* __restrict__ cond, const float* __restrict__ mw,
                           const float* __restrict__ mb, float* __restrict__ mod) {
    __shared__ float sc[Hc];
    int b = blockIdx.y;
    int tid = threadIdx.x;
    for (int i = tid; i < Hc; i += 256) {
        float c = cond[b*Hc + i];
        sc[i] = c / (1.f + __expf(-c));
    }
    __syncthreads();
    int j = blockIdx.x*256 + tid;
    const float* wr = mw + (size_t)j*Hc;
    float acc = 0.f;
    #pragma unroll 8
    for (int i = 0; i < Hc; ++i) acc += sc[i]*wr[i];
    mod[b*H6 + j] = acc + mb[j];
}

// ---------------- layernorm(x)*(1+scale)+shift -> bf16 (optionally padded) ------
template<bool PAD>
__global__ void ln_mod_kernel(const float* __restrict__ x, const float* __restrict__ mod,
                              int shoff, int scoff, u16* __restrict__ out) {
    int m = blockIdx.x;
    int b = m >> 11;
    int tid = threadIdx.x;
    float4 v = ((const float4*)(x + (size_t)m*Hc))[tid];
    float s1 = v.x+v.y+v.z+v.w;
    float s2 = v.x*v.x + v.y*v.y + v.z*v.z + v.w*v.w;
    s1 = wave_reduce_sum(s1); s2 = wave_reduce_sum(s2);
    __shared__ float red[8];
    int wid = tid >> 6, lane = tid & 63;
    if (lane == 0) { red[wid] = s1; red[4+wid] = s2; }
    __syncthreads();
    s1 = red[0]+red[1]+red[2]+red[3];
    s2 = red[4]+red[5]+red[6]+red[7];
    float mean = s1 * (1.f/Hc);
    float var  = s2 * (1.f/Hc) - mean*mean;
    float inv  = rsqrtf(var + 1e-5f);
    float4 shv = ((const float4*)(mod + b*H6 + shoff))[tid];
    float4 scv = ((const float4*)(mod + b*H6 + scoff))[tid];
    ushort4 o;
    o.x = f2b((v.x-mean)*inv*(1.f+scv.x)+shv.x);
    o.y = f2b((v.y-mean)*inv*(1.f+scv.y)+shv.y);
    o.z = f2b((v.z-mean)*inv*(1.f+scv.z)+shv.z);
    o.w = f2b((v.w-mean)*inv*(1.f+scv.w)+shv.w);
    size_t row = PAD ? ((size_t)b*LPAD + 1 + (m & 2047)) : (size_t)m;
    ((ushort4*)(out + row*Hc))[tid] = o;
}

// ---------------- weight converters ----------------
__global__ void cvt_plain(const float* __restrict__ src, u16* __restrict__ dst, int n) {
    int i = (blockIdx.x*256 + threadIdx.x)*4;
    if (i < n) {
        float4 v = *(const float4*)(src + i);
        ushort4 o; o.x=f2b(v.x); o.y=f2b(v.y); o.z=f2b(v.z); o.w=f2b(v.w);
        *(ushort4*)(dst + i) = o;
    }
}
__global__ void cvt_conv(const float* __restrict__ src, u16* __restrict__ dst, int NK) {
    int i = blockIdx.x*256 + threadIdx.x;
    if (i < NK) {
        float a = src[(size_t)i*3], b = src[(size_t)i*3+1], c = src[(size_t)i*3+2];
        dst[i] = f2b(a); dst[NK + i] = f2b(b); dst[2*NK + i] = f2b(c);
    }
}
__global__ void zero_pads(u16* __restrict__ p, int Kw) {
    int t = blockIdx.x*256 + threadIdx.x;
    if (t >= 4*Kw) return;
    int rr = t / Kw, c = t - rr*Kw;
    int row = (rr >> 1)*2050 + (rr & 1)*2049;   // 0, 2049, 2050, 4099
    p[(size_t)row*Kw + c] = 0;
}

// ---------------- MFMA GEMM / conv1d(k=3) -------------------------------------
// C[M,N] = sum_t shift(A,t-1) @ W[t].T ; A bf16 (padded rows when TAPS==3),
// W bf16 [TAPS][N][K]. 128x128 tile, 4 waves (2x2), BK=32, global_load_lds.
// EPI: 0 = +bias -> bf16 ; 1 = prev + gate*(acc+bias) -> f32 ;
//      2 = plain bf16 ; 3 = silu(other)*acc -> bf16 padded
template<int TAPS, int EPI, int N, int K>
__global__ void mfma_gemm(const u16* __restrict__ A, const u16* __restrict__ W,
                          const float* __restrict__ bias, const float* __restrict__ prev,
                          const u16* __restrict__ other,
                          const float* __restrict__ mod, int gate_off,
                          void* __restrict__ Cout)
{
    __shared__ u16 As[128*32];
    __shared__ u16 Bs[128*32];
    const int tid = threadIdx.x;
    const int w = tid >> 6, lane = tid & 63;
    const int wm = w >> 1, wn = w & 1;
    const int m0 = blockIdx.y * 128, n0 = blockIdx.x * 128;
    const int brow = m0 >> 11;
    f32x4 acc[4][4] = {};

    const int srow = lane >> 2;          // staging: row within 16-row chunk
    const int scol = (lane & 3) * 8;     // staging: k element offset
    const int frow = lane & 15;          // fragment row
    const int fke  = (lane >> 4) * 8;    // fragment k element offset

    for (int t = 0; t < TAPS; ++t) {
        const u16* Abase = A + ((TAPS == 3) ? ((size_t)(brow*LPAD + (m0 & 2047) + t))*K
                                            : (size_t)m0*K);
        const u16* Wt = W + (size_t)t*N*K;
        for (int k0 = 0; k0 < K; k0 += 32) {
            __syncthreads();
            #pragma unroll
            for (int ii = 0; ii < 2; ++ii) {
                const int ib = w + ii*4;                       // 0..7
                async16(&As[ib*512], Abase + (size_t)(ib*16 + srow)*K + k0 + scol);
                async16(&Bs[ib*512], Wt + (size_t)(n0 + ib*16 + srow)*K + k0 + scol);
            }
            __syncthreads();
            bf16x8 a[4], b[4];
            #pragma unroll
            for (int f = 0; f < 4; ++f) {
                a[f] = *(const bf16x8*)&As[(wm*64 + f*16 + frow)*32 + fke];
                b[f] = *(const bf16x8*)&Bs[(wn*64 + f*16 + frow)*32 + fke];
            }
            #pragma unroll
            for (int fi = 0; fi < 4; ++fi)
                #pragma unroll
                for (int fj = 0; fj < 4; ++fj)
                    acc[fi][fj] = __builtin_amdgcn_mfma_f32_16x16x32_bf16(
                        a[fi], b[fj], acc[fi][fj], 0, 0, 0);
        }
    }
    // epilogue: D row=(lane>>4)*4+reg, col=lane&15  [verified m89]
    #pragma unroll
    for (int fi = 0; fi < 4; ++fi) {
        #pragma unroll
        for (int i = 0; i < 4; ++i) {
            const int gm = m0 + wm*64 + fi*16 + (lane >> 4)*4 + i;
            const int bb = gm >> 11;
            #pragma unroll
            for (int fj = 0; fj < 4; ++fj) {
                const int col = n0 + wn*64 + fj*16 + frow;
                float r = acc[fi][fj][i];
                if (EPI == 0) {
                    ((u16*)Cout)[(size_t)gm*N + col] = f2b(r + bias[col]);
                } else if (EPI == 1) {
                    if (bias) r += bias[col];
                    const float g = mod[bb*H6 + gate_off + col];
                    ((float*)Cout)[(size_t)gm*N + col] =
                        prev[(size_t)gm*N + col] + g*r;
                } else if (EPI == 2) {
                    ((u16*)Cout)[(size_t)gm*N + col] = f2b(r);
                } else {
                    const float h = b2f(other[(size_t)gm*N + col]);
                    const float v = h / (1.f + __expf(-h)) * r;
                    ((u16*)Cout)[((size_t)bb*LPAD + 1 + (gm & 2047))*N + col] = f2b(v);
                }
            }
        }
    }
}

// ---------------- RMSNorm + RoPE + split qkv (bf16 in/out) ----------------
__global__ void rope_rms(const u16* __restrict__ qkv,
                         const float* __restrict__ qn_w, const float* __restrict__ kn_w,
                         const float* __restrict__ fcos, const float* __restrict__ fsin,
                         u16* __restrict__ Q, u16* __restrict__ K, u16* __restrict__ V) {
    int bh = blockIdx.y;
    int l  = blockIdx.x*4 + (threadIdx.x >> 6);
    int d  = threadIdx.x & 63;
    int b  = bh >> 4, h = bh & 15;
    size_t base = ((size_t)(b*Lc + l))*3072 + (size_t)(h*64 + d)*3;
    float qv = b2f(qkv[base + 0]);
    float kv = b2f(qkv[base + 1]);
    float vv = b2f(qkv[base + 2]);
    float qs = wave_reduce_sum(qv*qv) * (1.f/64.f);
    float ks = wave_reduce_sum(kv*kv) * (1.f/64.f);
    float qn = qv * rsqrtf(qs + 1e-6f) * qn_w[d];
    float kn = kv * rsqrtf(ks + 1e-6f) * kn_w[d];
    float c = fcos[l*64 + d], s = fsin[l*64 + d];
    float qp = __shfl_xor(qn, 1, 64);
    float kp = __shfl_xor(kn, 1, 64);
    float qr = (d & 1) ? qp : -qp;
    float kr = (d & 1) ? kp : -kp;
    size_t o = ((size_t)bh*Lc + l)*64 + d;
    Q[o] = f2b(qn*c + qr*s);
    K[o] = f2b(kn*c + kr*s);
    V[o] = f2b(vv);
}

// ---------------- V transpose: [bh][l][64] -> [bh][64][l] ----------------
__global__ void vtrans(const u16* __restrict__ V, u16* __restrict__ Vt) {
    __shared__ u16 t[64][65];
    int bh = blockIdx.y, l0 = blockIdx.x*64;
    int tid = threadIdx.x;
    #pragma unroll
    for (int p = 0; p < 16; ++p) {
        int idx = p*256 + tid; int r = idx >> 6, c = idx & 63;
        t[r][c] = V[((size_t)bh*Lc + l0 + r)*64 + c];
    }
    __syncthreads();
    #pragma unroll
    for (int p = 0; p < 16; ++p) {
        int idx = p*256 + tid; int d = idx >> 6, c = idx & 63;
        Vt[((size_t)bh*64 + d)*Lc + l0 + c] = t[c][d];
    }
}

// ---------------- flash attention (MFMA, online softmax) ----------------
// grid (L/64, B*NH), 256 thr. Wave w owns 16 q-rows. KV tiles of 64,
// K/V LDS XOR-swizzled (128B rows would be 16-way conflicts otherwise).
__global__ void attn_kernel(const u16* __restrict__ Q, const u16* __restrict__ K,
                            const u16* __restrict__ Vt, u16* __restrict__ Opad)
{
    __shared__ u16 Ks[64*64];
    __shared__ u16 Vs[64*64];
    __shared__ u16 Ps[4*16*72];     // per-wave P tile, stride 72 (16B-aligned rows)
    const int tid = threadIdx.x;
    const int w = tid >> 6, lane = tid & 63;
    const int bh = blockIdx.y;
    const int q0 = blockIdx.x * 64;
    const u16* Qb = Q  + (size_t)bh*Lc*64;
    const u16* Kb = K  + (size_t)bh*Lc*64;
    const u16* Vb = Vt + (size_t)bh*Lc*64;   // [64 d][2048 kv]
    const int frow = lane & 15;
    const int g4 = lane >> 4;
    bf16x8 qa[2];
    #pragma unroll
    for (int ks = 0; ks < 2; ++ks)
        qa[ks] = *(const bf16x8*)&Qb[(size_t)(q0 + w*16 + frow)*64 + ks*32 + g4*8];
    f32x4 o[4] = {};
    float m_[4], l_[4];
    #pragma unroll
    for (int i = 0; i < 4; ++i) { m_[i] = -1e30f; l_[i] = 0.f; }
    const int sr = lane >> 3;                 // staging row within 8-chunk
    const int sg = ((lane & 7) ^ sr) * 8;     // pre-swizzled source slot

    for (int kv0 = 0; kv0 < Lc; kv0 += 64) {
        __syncthreads();
        #pragma unroll
        for (int ii = 0; ii < 2; ++ii) {
            const int ib = w + ii*4;
            async16(&Ks[ib*512], Kb + (size_t)(kv0 + ib*8 + sr)*64 + sg);
            async16(&Vs[ib*512], Vb + (size_t)(ib*8 + sr)*Lc + kv0 + sg);
        }
        __syncthreads();
        // S = Q K^T (16x64, K-dim 64)
        f32x4 s[4] = {};
        #pragma unroll
        for (int fj = 0; fj < 4; ++fj)
            #pragma unroll
            for (int ks = 0; ks < 2; ++ks) {
                const int row = fj*16 + frow;
                bf16x8 kb = *(const bf16x8*)((const char*)Ks +
                            row*128 + (((g4 + 4*ks) ^ (frow & 7))*16));
                s[fj] = __builtin_amdgcn_mfma_f32_16x16x32_bf16(qa[ks], kb, s[fj], 0,0,0);
            }
        // online softmax (rows 4*g4+i, 16-lane col groups)
        #pragma unroll
        for (int i = 0; i < 4; ++i) {
            float mx = fmaxf(fmaxf(s[0][i], s[1][i]), fmaxf(s[2][i], s[3][i])) * 0.125f;
            #pragma unroll
            for (int d = 1; d < 16; d <<= 1) mx = fmaxf(mx, __shfl_xor(mx, d, 64));
            const float mn = fmaxf(m_[i], mx);
            const float al = __expf(m_[i] - mn);
            m_[i] = mn; l_[i] *= al;
            #pragma unroll
            for (int fd = 0; fd < 4; ++fd) o[fd][i] *= al;
            float rs = 0.f;
            #pragma unroll
            for (int fj = 0; fj < 4; ++fj) {
                const float p = __expf(s[fj][i]*0.125f - mn);
                s[fj][i] = p; rs += p;
            }
            #pragma unroll
            for (int d = 1; d < 16; d <<= 1) rs += __shfl_xor(rs, d, 64);
            l_[i] += rs;
        }
        // P -> LDS (bf16), then PV
        #pragma unroll
        for (int fj = 0; fj < 4; ++fj)
            #pragma unroll
            for (int i = 0; i < 4; ++i)
                Ps[w*1152 + (g4*4 + i)*72 + frow + 16*fj] = f2b(s[fj][i]);
        __syncthreads();
        #pragma unroll
        for (int ks = 0; ks < 2; ++ks) {
            bf16x8 pa = *(const bf16x8*)&Ps[w*1152 + frow*72 + ks*32 + g4*8];
            #pragma unroll
            for (int fd = 0; fd < 4; ++fd) {
                const int row = fd*16 + frow;
                bf16x8 va = *(const bf16x8*)((const char*)Vs +
                            row*128 + (((g4 + 4*ks) ^ (frow & 7))*16));
                o[fd] = __builtin_amdgcn_mfma_f32_16x16x32_bf16(pa, va, o[fd], 0,0,0);
            }
        }
    }
    const int b = bh >> 4, h = bh & 15;
    #pragma unroll
    for (int i = 0; i < 4; ++i) {
        const float inv = 1.f / l_[i];
        const int lq = q0 + w*16 + g4*4 + i;
        const size_t prow = (size_t)b*LPAD + 1 + lq;
        #pragma unroll
        for (int fd = 0; fd < 4; ++fd)
            Opad[prow*Hc + h*64 + fd*16 + frow] = f2b(o[fd][i]*inv);
    }
}

extern "C" void kernel_launch(void* const* d_in, const int* in_sizes, int n_in,
                              void* d_out, int out_size, void* d_ws, size_t ws_size,
                              hipStream_t stream) {
    const float* x      = (const float*)d_in[0];
    const float* cond   = (const float*)d_in[1];
    const float* fcos   = (const float*)d_in[2];
    const float* fsin   = (const float*)d_in[3];
    const float* mod_w  = (const float*)d_in[4];
    const float* mod_b  = (const float*)d_in[5];
    const float* qkv_w  = (const float*)d_in[6];
    const float* qkv_b  = (const float*)d_in[7];
    const float* qn_w   = (const float*)d_in[8];
    const float* kn_w   = (const float*)d_in[9];
    const float* lin1_w = (const float*)d_in[10];
    const float* lin1_b = (const float*)d_in[11];
    const float* w1     = (const float*)d_in[12];
    const float* w2     = (const float*)d_in[13];
    const float* w3     = (const float*)d_in[14];
    float* out = (float*)d_out;
    char* wsb  = (char*)d_ws;

    float* mod  = (float*)(wsb + 0);                       // 48 KB
    u16* Wslot  = (u16*)(wsb + (1u<<16));                  // <=16.5 MiB, reused
    u16* Breg   = (u16*)(wsb + 18u*1024*1024);             // xn1 -> attn_pad
    u16* Creg   = (u16*)(wsb + 27u*1024*1024);             // qkv -> h1a
    u16* Dreg   = (u16*)(wsb + 52u*1024*1024);             // Q,K,V,Vt -> xn2_pad
    u16* Ereg   = (u16*)(wsb + 86u*1024*1024);             // h1_pad

    u16* xn1  = Breg;
    u16* apad = Breg;
    u16* qkvb = Creg;
    u16* h1a  = Creg;
    u16* Qb = Dreg;
    u16* Kb = Dreg + 4194304;
    u16* Vb = Dreg + 8388608;
    u16* Vt = Dreg + 12582912;
    u16* xn2p = Dreg;
    u16* h1p  = Ereg;

    dim3 blk(256);
    mod_kernel<<<dim3(H6/256, Bc), blk, 0, stream>>>(cond, mod_w, mod_b, mod);
    zero_pads<<<dim3((4*2816 + 255)/256), blk, 0, stream>>>(h1p, 2816);
    ln_mod_kernel<false><<<Mc, blk, 0, stream>>>(x, mod, 0, Hc, xn1);
    cvt_plain<<<dim3((3072*1024/4 + 255)/256), blk, 0, stream>>>(qkv_w, Wslot, 3072*1024);
    mfma_gemm<1,0,3072,1024><<<dim3(24,32), blk, 0, stream>>>(
        xn1, Wslot, qkv_b, nullptr, nullptr, nullptr, 0, qkvb);
    zero_pads<<<dim3((4*1024 + 255)/256), blk, 0, stream>>>(apad, 1024);   // xn1 dead now
    rope_rms<<<dim3(Lc/4, 32), blk, 0, stream>>>(qkvb, qn_w, kn_w, fcos, fsin, Qb, Kb, Vb);
    vtrans<<<dim3(32, 32), blk, 0, stream>>>(Vb, Vt);
    attn_kernel<<<dim3(32, 32), blk, 0, stream>>>(Qb, Kb, Vt, apad);
    cvt_conv<<<dim3((1024*1024 + 255)/256), blk, 0, stream>>>(lin1_w, Wslot, 1024*1024);
    mfma_gemm<3,1,1024,1024><<<dim3(8,32), blk, 0, stream>>>(
        apad, Wslot, lin1_b, x, nullptr, mod, 2*Hc, (void*)out);
    zero_pads<<<dim3((4*1024 + 255)/256), blk, 0, stream>>>(xn2p, 1024);   // Q..Vt dead now
    ln_mod_kernel<true><<<Mc, blk, 0, stream>>>(out, mod, 3*Hc, 4*Hc, xn2p);
    cvt_conv<<<dim3((2816*1024 + 255)/256), blk, 0, stream>>>(w1, Wslot, 2816*1024);
    mfma_gemm<3,2,2816,1024><<<dim3(22,32), blk, 0, stream>>>(
        xn2p, Wslot, nullptr, nullptr, nullptr, nullptr, 0, h1a);
    cvt_conv<<<dim3((2816*1024 + 255)/256), blk, 0, stream>>>(w3, Wslot, 2816*1024);
    mfma_gemm<3,3,2816,1024><<<dim3(22,32), blk, 0, stream>>>(
        xn2p, Wslot, nullptr, nullptr, h1a, nullptr, 0, h1p);
    cvt_conv<<<dim3((1024*2816 + 255)/256), blk, 0, stream>>>(w2, Wslot, 1024*2816);
    mfma_gemm<3,1,1024,2816><<<dim3(8,32), blk, 0, stream>>>(
        h1p, Wslot, nullptr, out, nullptr, mod, 5*Hc, (void*)out);
    (void)in_sizes; (void)n_in; (void)out_size; (void)ws_size;
}

// Round 3
// 571.688 us; speedup vs baseline: 17.8961x; 1.2043x over previous
//
#include <hip/hip_runtime.h>
#include <math.h>

typedef unsigned short u16;
typedef __attribute__((ext_vector_type(8))) short bf16x8;   // 8 bf16 (4 VGPRs)
typedef __attribute__((ext_vector_type(4))) float f32x4;

#define Bc   2
#define Lc   2048
#define Hc   1024
#define H6   6144
#define Mc   4096          // B*L
#define LPAD 2050          // padded rows per batch (1 zero row each side)

__device__ __forceinline__ u16 f2b(float f) {
    union { float f; unsigned u; } x; x.f = f;
    unsigned r = x.u + 0x7fffu + ((x.u >> 16) & 1u);
    return (u16)(r >> 16);
}
__device__ __forceinline__ float b2f(u16 h) {
    union { unsigned u; float f; } x; x.u = ((unsigned)h) << 16;
    return x.f;
}
__device__ __forceinline__ void async16(u16* lds, const u16* g) {
    __builtin_amdgcn_global_load_lds((const __attribute__((address_space(1))) void*)g,
                                     (__attribute__((address_space(3))) void*)lds, 16, 0, 0);
}
__device__ __forceinline__ float wave_reduce_sum(float v) {
    #pragma unroll
    for (int m = 1; m < 64; m <<= 1) v += __shfl_xor(v, m, 64);
    return v;
}

// ---------------- mod = silu(cond) @ mod_w.T + mod_b (f32, tiny) ----------------
__global__ void mod_kernel(const float* __restrict__ cond, const float* __restrict__ mw,
                           const float* __restrict__ mb, float* __restrict__ mod) {
    __shared__ float sc[Hc];
    int b = blockIdx.y;
    int tid = threadIdx.x;
    for (int i = tid; i < Hc; i += 256) {
        float c = cond[b*Hc + i];
        sc[i] = c / (1.f + __expf(-c));
    }
    __syncthreads();
    int j = blockIdx.x*256 + tid;
    const float* wr = mw + (size_t)j*Hc;
    float acc = 0.f;
    #pragma unroll 8
    for (int i = 0; i < Hc; ++i) acc += sc[i]*wr[i];
    mod[b*H6 + j] = acc + mb[j];
}

// ---------------- layernorm(x)*(1+scale)+shift -> bf16 (optionally padded) ------
template<bool PAD>
__global__ void ln_mod_kernel(const float* __restrict__ x, const float* __restrict__ mod,
                              int shoff, int scoff, u16* __restrict__ out) {
    int m = blockIdx.x;
    int b = m >> 11;
    int tid = threadIdx.x;
    float4 v = ((const float4*)(x + (size_t)m*Hc))[tid];
    float s1 = v.x+v.y+v.z+v.w;
    float s2 = v.x*v.x + v.y*v.y + v.z*v.z + v.w*v.w;
    s1 = wave_reduce_sum(s1); s2 = wave_reduce_sum(s2);
    __shared__ float red[8];
    int wid = tid >> 6, lane = tid & 63;
    if (lane == 0) { red[wid] = s1; red[4+wid] = s2; }
    __syncthreads();
    s1 = red[0]+red[1]+red[2]+red[3];
    s2 = red[4]+red[5]+red[6]+red[7];
    float mean = s1 * (1.f/Hc);
    float var  = s2 * (1.f/Hc) - mean*mean;
    float inv  = rsqrtf(var + 1e-5f);
    float4 shv = ((const float4*)(mod + b*H6 + shoff))[tid];
    float4 scv = ((const float4*)(mod + b*H6 + scoff))[tid];
    ushort4 o;
    o.x = f2b((v.x-mean)*inv*(1.f+scv.x)+shv.x);
    o.y = f2b((v.y-mean)*inv*(1.f+scv.y)+shv.y);
    o.z = f2b((v.z-mean)*inv*(1.f+scv.z)+shv.z);
    o.w = f2b((v.w-mean)*inv*(1.f+scv.w)+shv.w);
    size_t row = PAD ? ((size_t)b*LPAD + 1 + (m & 2047)) : (size_t)m;
    ((ushort4*)(out + row*Hc))[tid] = o;
}

// ---------------- weight converters ----------------
__global__ void cvt_plain(const float* __restrict__ src, u16* __restrict__ dst, int n) {
    int i = (blockIdx.x*256 + threadIdx.x)*4;
    if (i < n) {
        float4 v = *(const float4*)(src + i);
        ushort4 o; o.x=f2b(v.x); o.y=f2b(v.y); o.z=f2b(v.z); o.w=f2b(v.w);
        *(ushort4*)(dst + i) = o;
    }
}
__global__ void cvt_conv(const float* __restrict__ src, u16* __restrict__ dst, int NK) {
    int i = blockIdx.x*256 + threadIdx.x;
    if (i < NK) {
        float a = src[(size_t)i*3], b = src[(size_t)i*3+1], c = src[(size_t)i*3+2];
        dst[i] = f2b(a); dst[NK + i] = f2b(b); dst[2*NK + i] = f2b(c);
    }
}
__global__ void zero_pads(u16* __restrict__ p, int Kw) {
    int t = blockIdx.x*256 + threadIdx.x;
    if (t >= 4*Kw) return;
    int rr = t / Kw, c = t - rr*Kw;
    int row = (rr >> 1)*2050 + (rr & 1)*2049;   // 0, 2049, 2050, 4099
    p[(size_t)row*Kw + c] = 0;
}

// ---------------- MFMA GEMM / conv1d(k=3), A-slab shared across taps ----------
// C[M,N] = sum_t shift(A,t-1) @ W[t].T ; A bf16 (padded rows when TAPS==3),
// W bf16 [TAPS][N][K]. 128x128 tile, 4 waves (2x2), BK=64.
// LDS rows are 128B, XOR-swizzled (slot ^= row&7) via pre-swizzled global src.
// EPI: 0 = +bias -> bf16 ; 1 = prev + gate*(acc+bias) -> f32 ;
//      2 = plain bf16 ; 3 = silu(other)*acc -> bf16 padded
template<int TAPS, int EPI, int N, int K>
__global__ __launch_bounds__(256, 2)
void conv_gemm(const u16* __restrict__ A, const u16* __restrict__ W,
               const float* __restrict__ bias, const float* __restrict__ prev,
               const u16* __restrict__ other,
               const float* __restrict__ mod, int gate_off,
               void* __restrict__ Cout)
{
    constexpr int AROWS = (TAPS == 3) ? 136 : 128;
    __shared__ __align__(16) u16 As[AROWS*64];
    __shared__ __align__(16) u16 Ws[TAPS*128*64];

    const int tid = threadIdx.x;
    const int w = tid >> 6, lane = tid & 63;
    const int wm = w >> 1, wn = w & 1;

    // bijective XCD-chunk swizzle (all grids are multiples of 8 blocks)
    const int nwg  = gridDim.x * gridDim.y;
    const int orig = blockIdx.x + gridDim.x * blockIdx.y;
    const int wg   = (orig & 7)*(nwg >> 3) + (orig >> 3);
    const int tm = wg & 31;          // gridDim.y == 32 always (M tiles)
    const int tn = wg >> 5;
    const int m0 = tm*128, n0 = tn*128;
    const int brow = m0 >> 11;

    const u16* Abase = (TAPS == 3) ? A + ((size_t)brow*LPAD + (m0 & 2047))*K
                                   : A + (size_t)m0*K;

    const int lr  = lane >> 3;                 // row within 8-row chunk
    const int lsw = ((lane & 7) ^ lr) * 8;     // pre-swizzled k-slot (elems)

    const int frow = lane & 15;
    const int fsl  = lane >> 4;                // 0..3

    f32x4 acc[4][4] = {};

    for (int k0 = 0; k0 < K; k0 += 64) {
        __syncthreads();
        // ---- stage A: chunks w, w+4, w+8, w+12 (rows 8 each) ----
        {
            const u16* asrc = Abase + (size_t)(w*8 + lr)*K + k0 + lsw;
            #pragma unroll
            for (int i = 0; i < 4; ++i) {
                const int c = w + i*4;
                async16(&As[c*512], asrc + (size_t)(i*32)*K);
            }
            if (TAPS == 3 && w == 0) {          // chunk 16: rows 128..135 (need <=129)
                int row = 128 + lr; if (row > 129) row = 129;
                async16(&As[16*512], Abase + (size_t)row*K + k0 + lsw);
            }
        }
        // ---- stage W: TAPS*16 chunks, 12 (or 4) per wave ----
        #pragma unroll
        for (int j = 0; j < TAPS*4; ++j) {
            const int c2 = w + j*4;
            async16(&Ws[c2*512],
                    W + ((size_t)(c2 >> 4)*N + n0 + (c2 & 15)*8 + lr)*K + k0 + lsw);
        }
        __syncthreads();

        // ---- compute: TAPS * 32 MFMA per wave ----
        #pragma unroll
        for (int t = 0; t < TAPS; ++t) {
            bf16x8 a[4][2], b[4][2];
            #pragma unroll
            for (int f = 0; f < 4; ++f) {
                const int ar = wm*64 + f*16 + frow + ((TAPS == 3) ? t : 0);
                const int br = wn*64 + f*16 + frow;
                #pragma unroll
                for (int ks = 0; ks < 2; ++ks) {
                    a[f][ks] = *(const bf16x8*)&As[ar*64 + (((ks*4 + fsl) ^ (ar & 7))*8)];
                    b[f][ks] = *(const bf16x8*)&Ws[(t*128 + br)*64 + (((ks*4 + fsl) ^ (br & 7))*8)];
                }
            }
            #pragma unroll
            for (int fi = 0; fi < 4; ++fi)
                #pragma unroll
                for (int fj = 0; fj < 4; ++fj)
                    #pragma unroll
                    for (int ks = 0; ks < 2; ++ks)
                        acc[fi][fj] = __builtin_amdgcn_mfma_f32_16x16x32_bf16(
                            a[fi][ks], b[fj][ks], acc[fi][fj], 0, 0, 0);
        }
    }

    // epilogue: D row=(lane>>4)*4+reg, col=lane&15  [verified m89]
    #pragma unroll
    for (int fi = 0; fi < 4; ++fi) {
        #pragma unroll
        for (int i = 0; i < 4; ++i) {
            const int gm = m0 + wm*64 + fi*16 + (lane >> 4)*4 + i;
            const int bb = gm >> 11;
            #pragma unroll
            for (int fj = 0; fj < 4; ++fj) {
                const int col = n0 + wn*64 + fj*16 + frow;
                float r = acc[fi][fj][i];
                if (EPI == 0) {
                    ((u16*)Cout)[(size_t)gm*N + col] = f2b(r + bias[col]);
                } else if (EPI == 1) {
                    if (bias) r += bias[col];
                    const float g = mod[bb*H6 + gate_off + col];
                    ((float*)Cout)[(size_t)gm*N + col] =
                        prev[(size_t)gm*N + col] + g*r;
                } else if (EPI == 2) {
                    ((u16*)Cout)[(size_t)gm*N + col] = f2b(r);
                } else {
                    const float h = b2f(other[(size_t)gm*N + col]);
                    const float v = h / (1.f + __expf(-h)) * r;
                    ((u16*)Cout)[((size_t)bb*LPAD + 1 + (gm & 2047))*N + col] = f2b(v);
                }
            }
        }
    }
}

// ---------------- RMSNorm + RoPE + split qkv (bf16 in/out) ----------------
__global__ void rope_rms(const u16* __restrict__ qkv,
                         const float* __restrict__ qn_w, const float* __restrict__ kn_w,
                         const float* __restrict__ fcos, const float* __restrict__ fsin,
                         u16* __restrict__ Q, u16* __restrict__ K, u16* __restrict__ V) {
    int bh = blockIdx.y;
    int l  = blockIdx.x*4 + (threadIdx.x >> 6);
    int d  = threadIdx.x & 63;
    int b  = bh >> 4, h = bh & 15;
    size_t base = ((size_t)(b*Lc + l))*3072 + (size_t)(h*64 + d)*3;
    float qv = b2f(qkv[base + 0]);
    float kv = b2f(qkv[base + 1]);
    float vv = b2f(qkv[base + 2]);
    float qs = wave_reduce_sum(qv*qv) * (1.f/64.f);
    float ks = wave_reduce_sum(kv*kv) * (1.f/64.f);
    float qn = qv * rsqrtf(qs + 1e-6f) * qn_w[d];
    float kn = kv * rsqrtf(ks + 1e-6f) * kn_w[d];
    float c = fcos[l*64 + d], s = fsin[l*64 + d];
    float qp = __shfl_xor(qn, 1, 64);
    float kp = __shfl_xor(kn, 1, 64);
    float qr = (d & 1) ? qp : -qp;
    float kr = (d & 1) ? kp : -kp;
    size_t o = ((size_t)bh*Lc + l)*64 + d;
    Q[o] = f2b(qn*c + qr*s);
    K[o] = f2b(kn*c + kr*s);
    V[o] = f2b(vv);
}

// ---------------- V transpose: [bh][l][64] -> [bh][64][l] ----------------
__global__ void vtrans(const u16* __restrict__ V, u16* __restrict__ Vt) {
    __shared__ u16 t[64][65];
    int bh = blockIdx.y, l0 = blockIdx.x*64;
    int tid = threadIdx.x;
    #pragma unroll
    for (int p = 0; p < 16; ++p) {
        int idx = p*256 + tid; int r = idx >> 6, c = idx & 63;
        t[r][c] = V[((size_t)bh*Lc + l0 + r)*64 + c];
    }
    __syncthreads();
    #pragma unroll
    for (int p = 0; p < 16; ++p) {
        int idx = p*256 + tid; int d = idx >> 6, c = idx & 63;
        Vt[((size_t)bh*64 + d)*Lc + l0 + c] = t[c][d];
    }
}

// ---------------- flash attention (MFMA, online softmax) ----------------
__global__ void attn_kernel(const u16* __restrict__ Q, const u16* __restrict__ K,
                            const u16* __restrict__ Vt, u16* __restrict__ Opad)
{
    __shared__ u16 Ks[64*64];
    __shared__ u16 Vs[64*64];
    __shared__ u16 Ps[4*16*72];     // per-wave P tile, stride 72 (16B-aligned rows)
    const int tid = threadIdx.x;
    const int w = tid >> 6, lane = tid & 63;
    const int bh = blockIdx.y;
    const int q0 = blockIdx.x * 64;
    const u16* Qb = Q  + (size_t)bh*Lc*64;
    const u16* Kb = K  + (size_t)bh*Lc*64;
    const u16* Vb = Vt + (size_t)bh*Lc*64;   // [64 d][2048 kv]
    const int frow = lane & 15;
    const int g4 = lane >> 4;
    bf16x8 qa[2];
    #pragma unroll
    for (int ks = 0; ks < 2; ++ks)
        qa[ks] = *(const bf16x8*)&Qb[(size_t)(q0 + w*16 + frow)*64 + ks*32 + g4*8];
    f32x4 o[4] = {};
    float m_[4], l_[4];
    #pragma unroll
    for (int i = 0; i < 4; ++i) { m_[i] = -1e30f; l_[i] = 0.f; }
    const int sr = lane >> 3;                 // staging row within 8-chunk
    const int sg = ((lane & 7) ^ sr) * 8;     // pre-swizzled source slot

    for (int kv0 = 0; kv0 < Lc; kv0 += 64) {
        __syncthreads();
        #pragma unroll
        for (int ii = 0; ii < 2; ++ii) {
            const int ib = w + ii*4;
            async16(&Ks[ib*512], Kb + (size_t)(kv0 + ib*8 + sr)*64 + sg);
            async16(&Vs[ib*512], Vb + (size_t)(ib*8 + sr)*Lc + kv0 + sg);
        }
        __syncthreads();
        // S = Q K^T (16x64, K-dim 64)
        f32x4 s[4] = {};
        #pragma unroll
        for (int fj = 0; fj < 4; ++fj)
            #pragma unroll
            for (int ks = 0; ks < 2; ++ks) {
                const int row = fj*16 + frow;
                bf16x8 kb = *(const bf16x8*)((const char*)Ks +
                            row*128 + (((g4 + 4*ks) ^ (frow & 7))*16));
                s[fj] = __builtin_amdgcn_mfma_f32_16x16x32_bf16(qa[ks], kb, s[fj], 0,0,0);
            }
        // online softmax (rows 4*g4+i, 16-lane col groups)
        #pragma unroll
        for (int i = 0; i < 4; ++i) {
            float mx = fmaxf(fmaxf(s[0][i], s[1][i]), fmaxf(s[2][i], s[3][i])) * 0.125f;
            #pragma unroll
            for (int d = 1; d < 16; d <<= 1) mx = fmaxf(mx, __shfl_xor(mx, d, 64));
            const float mn = fmaxf(m_[i], mx);
            const float al = __expf(m_[i] - mn);
            m_[i] = mn; l_[i] *= al;
            #pragma unroll
            for (int fd = 0; fd < 4; ++fd) o[fd][i] *= al;
            float rs = 0.f;
            #pragma unroll
            for (int fj = 0; fj < 4; ++fj) {
                const float p = __expf(s[fj][i]*0.125f - mn);
                s[fj][i] = p; rs += p;
            }
            #pragma unroll
            for (int d = 1; d < 16; d <<= 1) rs += __shfl_xor(rs, d, 64);
            l_[i] += rs;
        }
        // P -> LDS (bf16), then PV
        #pragma unroll
        for (int fj = 0; fj < 4; ++fj)
            #pragma unroll
            for (int i = 0; i < 4; ++i)
                Ps[w*1152 + (g4*4 + i)*72 + frow + 16*fj] = f2b(s[fj][i]);
        __syncthreads();
        #pragma unroll
        for (int ks = 0; ks < 2; ++ks) {
            bf16x8 pa = *(const bf16x8*)&Ps[w*1152 + frow*72 + ks*32 + g4*8];
            #pragma unroll
            for (int fd = 0; fd < 4; ++fd) {
                const int row = fd*16 + frow;
                bf16x8 va = *(const bf16x8*)((const char*)Vs +
                            row*128 + (((g4 + 4*ks) ^ (frow & 7))*16));
                o[fd] = __builtin_amdgcn_mfma_f32_16x16x32_bf16(pa, va, o[fd], 0,0,0);
            }
        }
    }
    const int b = bh >> 4, h = bh & 15;
    #pragma unroll
    for (int i = 0; i < 4; ++i) {
        const float inv = 1.f / l_[i];
        const int lq = q0 + w*16 + g4*4 + i;
        const size_t prow = (size_t)b*LPAD + 1 + lq;
        #pragma unroll
        for (int fd = 0; fd < 4; ++fd)
            Opad[prow*Hc + h*64 + fd*16 + frow] = f2b(o[fd][i]*inv);
    }
}

extern "C" void kernel_launch(void* const* d_in, const int* in_sizes, int n_in,
                              void* d_out, int out_size, void* d_ws, size_t ws_size,
                              hipStream_t stream) {
    const float* x      = (const float*)d_in[0];
    const float* cond   = (const float*)d_in[1];
    const float* fcos   = (const float*)d_in[2];
    const float* fsin   = (const float*)d_in[3];
    const float* mod_w  = (const float*)d_in[4];
    const float* mod_b  = (const float*)d_in[5];
    const float* qkv_w  = (const float*)d_in[6];
    const float* qkv_b  = (const float*)d_in[7];
    const float* qn_w   = (const float*)d_in[8];
    const float* kn_w   = (const float*)d_in[9];
    const float* lin1_w = (const float*)d_in[10];
    const float* lin1_b = (const float*)d_in[11];
    const float* w1     = (const float*)d_in[12];
    const float* w2     = (const float*)d_in[13];
    const float* w3     = (const float*)d_in[14];
    float* out = (float*)d_out;
    char* wsb  = (char*)d_ws;

    float* mod  = (float*)(wsb + 0);                       // 48 KB
    u16* Wslot  = (u16*)(wsb + (1u<<16));                  // <=16.5 MiB, reused
    u16* Breg   = (u16*)(wsb + 18u*1024*1024);             // xn1 -> attn_pad
    u16* Creg   = (u16*)(wsb + 27u*1024*1024);             // qkv -> h1a
    u16* Dreg   = (u16*)(wsb + 52u*1024*1024);             // Q,K,V,Vt -> xn2_pad
    u16* Ereg   = (u16*)(wsb + 86u*1024*1024);             // h1_pad

    u16* xn1  = Breg;
    u16* apad = Breg;
    u16* qkvb = Creg;
    u16* h1a  = Creg;
    u16* Qb = Dreg;
    u16* Kb = Dreg + 4194304;
    u16* Vb = Dreg + 8388608;
    u16* Vt = Dreg + 12582912;
    u16* xn2p = Dreg;
    u16* h1p  = Ereg;

    dim3 blk(256);
    mod_kernel<<<dim3(H6/256, Bc), blk, 0, stream>>>(cond, mod_w, mod_b, mod);
    zero_pads<<<dim3((4*2816 + 255)/256), blk, 0, stream>>>(h1p, 2816);
    ln_mod_kernel<false><<<Mc, blk, 0, stream>>>(x, mod, 0, Hc, xn1);
    cvt_plain<<<dim3((3072*1024/4 + 255)/256), blk, 0, stream>>>(qkv_w, Wslot, 3072*1024);
    conv_gemm<1,0,3072,1024><<<dim3(24,32), blk, 0, stream>>>(
        xn1, Wslot, qkv_b, nullptr, nullptr, nullptr, 0, qkvb);
    zero_pads<<<dim3((4*1024 + 255)/256), blk, 0, stream>>>(apad, 1024);   // xn1 dead now
    rope_rms<<<dim3(Lc/4, 32), blk, 0, stream>>>(qkvb, qn_w, kn_w, fcos, fsin, Qb, Kb, Vb);
    vtrans<<<dim3(32, 32), blk, 0, stream>>>(Vb, Vt);
    attn_kernel<<<dim3(32, 32), blk, 0, stream>>>(Qb, Kb, Vt, apad);
    cvt_conv<<<dim3((1024*1024 + 255)/256), blk, 0, stream>>>(lin1_w, Wslot, 1024*1024);
    conv_gemm<3,1,1024,1024><<<dim3(8,32), blk, 0, stream>>>(
        apad, Wslot, lin1_b, x, nullptr, mod, 2*Hc, (void*)out);
    zero_pads<<<dim3((4*1024 + 255)/256), blk, 0, stream>>>(xn2p, 1024);   // Q..Vt dead now
    ln_mod_kernel<true><<<Mc, blk, 0, stream>>>(out, mod, 3*Hc, 4*Hc, xn2p);
    cvt_conv<<<dim3((2816*1024 + 255)/256), blk, 0, stream>>>(w1, Wslot, 2816*1024);
    conv_gemm<3,2,2816,1024><<<dim3(22,32), blk, 0, stream>>>(
        xn2p, Wslot, nullptr, nullptr, nullptr, nullptr, 0, h1a);
    cvt_conv<<<dim3((2816*1024 + 255)/256), blk, 0, stream>>>(w3, Wslot, 2816*1024);
    conv_gemm<3,3,2816,1024><<<dim3(22,32), blk, 0, stream>>>(
        xn2p, Wslot, nullptr, nullptr, h1a, nullptr, 0, h1p);
    cvt_conv<<<dim3((1024*2816 + 255)/256), blk, 0, stream>>>(w2, Wslot, 1024*2816);
    conv_gemm<3,1,1024,2816><<<dim3(8,32), blk, 0, stream>>>(
        h1p, Wslot, nullptr, out, nullptr, mod, 5*Hc, (void*)out);
    (void)in_sizes; (void)n_in; (void)out_size; (void)ws_size;
}

// Round 4
// 520.577 us; speedup vs baseline: 19.6532x; 1.0982x over previous
//
#include <hip/hip_runtime.h>
#include <math.h>

typedef unsigned short u16;
typedef __attribute__((ext_vector_type(8))) short bf16x8;   // 8 bf16 (4 VGPRs)
typedef __attribute__((ext_vector_type(4))) float f32x4;
typedef __attribute__((ext_vector_type(16))) float f32x16;

#define Bc   2
#define Lc   2048
#define Hc   1024
#define H6   6144
#define Mc   4096          // B*L
#define LPAD 2050          // padded rows per batch (1 zero row each side)

__device__ __forceinline__ u16 f2b(float f) {
    union { float f; unsigned u; } x; x.f = f;
    unsigned r = x.u + 0x7fffu + ((x.u >> 16) & 1u);
    return (u16)(r >> 16);
}
__device__ __forceinline__ float b2f(u16 h) {
    union { unsigned u; float f; } x; x.u = ((unsigned)h) << 16;
    return x.f;
}
__device__ __forceinline__ void async16(u16* lds, const u16* g) {
    __builtin_amdgcn_global_load_lds((const __attribute__((address_space(1))) void*)g,
                                     (__attribute__((address_space(3))) void*)lds, 16, 0, 0);
}
__device__ __forceinline__ float wave_reduce_sum(float v) {
    #pragma unroll
    for (int m = 1; m < 64; m <<= 1) v += __shfl_xor(v, m, 64);
    return v;
}

// ---------------- mod = silu(cond) @ mod_w.T + mod_b (f32, tiny) ----------------
__global__ void mod_kernel(const float* __restrict__ cond, const float* __restrict__ mw,
                           const float* __restrict__ mb, float* __restrict__ mod) {
    __shared__ float sc[Hc];
    int b = blockIdx.y;
    int tid = threadIdx.x;
    for (int i = tid; i < Hc; i += 256) {
        float c = cond[b*Hc + i];
        sc[i] = c / (1.f + __expf(-c));
    }
    __syncthreads();
    int j = blockIdx.x*256 + tid;
    const float* wr = mw + (size_t)j*Hc;
    float acc = 0.f;
    #pragma unroll 8
    for (int i = 0; i < Hc; ++i) acc += sc[i]*wr[i];
    mod[b*H6 + j] = acc + mb[j];
}

// ---------------- layernorm(x)*(1+scale)+shift -> bf16 (optionally padded) ------
template<bool PAD>
__global__ void ln_mod_kernel(const float* __restrict__ x, const float* __restrict__ mod,
                              int shoff, int scoff, u16* __restrict__ out) {
    int m = blockIdx.x;
    int b = m >> 11;
    int tid = threadIdx.x;
    float4 v = ((const float4*)(x + (size_t)m*Hc))[tid];
    float s1 = v.x+v.y+v.z+v.w;
    float s2 = v.x*v.x + v.y*v.y + v.z*v.z + v.w*v.w;
    s1 = wave_reduce_sum(s1); s2 = wave_reduce_sum(s2);
    __shared__ float red[8];
    int wid = tid >> 6, lane = tid & 63;
    if (lane == 0) { red[wid] = s1; red[4+wid] = s2; }
    __syncthreads();
    s1 = red[0]+red[1]+red[2]+red[3];
    s2 = red[4]+red[5]+red[6]+red[7];
    float mean = s1 * (1.f/Hc);
    float var  = s2 * (1.f/Hc) - mean*mean;
    float inv  = rsqrtf(var + 1e-5f);
    float4 shv = ((const float4*)(mod + b*H6 + shoff))[tid];
    float4 scv = ((const float4*)(mod + b*H6 + scoff))[tid];
    ushort4 o;
    o.x = f2b((v.x-mean)*inv*(1.f+scv.x)+shv.x);
    o.y = f2b((v.y-mean)*inv*(1.f+scv.y)+shv.y);
    o.z = f2b((v.z-mean)*inv*(1.f+scv.z)+shv.z);
    o.w = f2b((v.w-mean)*inv*(1.f+scv.w)+shv.w);
    size_t row = PAD ? ((size_t)b*LPAD + 1 + (m & 2047)) : (size_t)m;
    ((ushort4*)(out + row*Hc))[tid] = o;
}

// ---------------- weight converters ----------------
__global__ void cvt_plain(const float* __restrict__ src, u16* __restrict__ dst, int n) {
    int i = (blockIdx.x*256 + threadIdx.x)*4;
    if (i < n) {
        float4 v = *(const float4*)(src + i);
        ushort4 o; o.x=f2b(v.x); o.y=f2b(v.y); o.z=f2b(v.z); o.w=f2b(v.w);
        *(ushort4*)(dst + i) = o;
    }
}
__global__ void cvt_conv(const float* __restrict__ src, u16* __restrict__ dst, int NK) {
    int i = blockIdx.x*256 + threadIdx.x;
    if (i < NK) {
        float a = src[(size_t)i*3], b = src[(size_t)i*3+1], c = src[(size_t)i*3+2];
        dst[i] = f2b(a); dst[NK + i] = f2b(b); dst[2*NK + i] = f2b(c);
    }
}
__global__ void zero_pads(u16* __restrict__ p, int Kw) {
    int t = blockIdx.x*256 + threadIdx.x;
    if (t >= 4*Kw) return;
    int rr = t / Kw, c = t - rr*Kw;
    int row = (rr >> 1)*2050 + (rr & 1)*2049;   // 0, 2049, 2050, 4099
    p[(size_t)row*Kw + c] = 0;
}

// ---------------- MFMA GEMM / conv1d(k=3), A-slab shared across taps ----------
template<int TAPS, int EPI, int N, int K>
__global__ __launch_bounds__(256, 2)
void conv_gemm(const u16* __restrict__ A, const u16* __restrict__ W,
               const float* __restrict__ bias, const float* __restrict__ prev,
               const u16* __restrict__ other,
               const float* __restrict__ mod, int gate_off,
               void* __restrict__ Cout)
{
    constexpr int AROWS = (TAPS == 3) ? 136 : 128;
    __shared__ __align__(16) u16 As[AROWS*64];
    __shared__ __align__(16) u16 Ws[TAPS*128*64];

    const int tid = threadIdx.x;
    const int w = tid >> 6, lane = tid & 63;
    const int wm = w >> 1, wn = w & 1;

    const int nwg  = gridDim.x * gridDim.y;
    const int orig = blockIdx.x + gridDim.x * blockIdx.y;
    const int wg   = (orig & 7)*(nwg >> 3) + (orig >> 3);
    const int tm = wg & 31;
    const int tn = wg >> 5;
    const int m0 = tm*128, n0 = tn*128;
    const int brow = m0 >> 11;

    const u16* Abase = (TAPS == 3) ? A + ((size_t)brow*LPAD + (m0 & 2047))*K
                                   : A + (size_t)m0*K;

    const int lr  = lane >> 3;
    const int lsw = ((lane & 7) ^ lr) * 8;

    const int frow = lane & 15;
    const int fsl  = lane >> 4;

    f32x4 acc[4][4] = {};

    for (int k0 = 0; k0 < K; k0 += 64) {
        __syncthreads();
        {
            const u16* asrc = Abase + (size_t)(w*8 + lr)*K + k0 + lsw;
            #pragma unroll
            for (int i = 0; i < 4; ++i) {
                const int c = w + i*4;
                async16(&As[c*512], asrc + (size_t)(i*32)*K);
            }
            if (TAPS == 3 && w == 0) {
                int row = 128 + lr; if (row > 129) row = 129;
                async16(&As[16*512], Abase + (size_t)row*K + k0 + lsw);
            }
        }
        #pragma unroll
        for (int j = 0; j < TAPS*4; ++j) {
            const int c2 = w + j*4;
            async16(&Ws[c2*512],
                    W + ((size_t)(c2 >> 4)*N + n0 + (c2 & 15)*8 + lr)*K + k0 + lsw);
        }
        __syncthreads();

        #pragma unroll
        for (int t = 0; t < TAPS; ++t) {
            bf16x8 a[4][2], b[4][2];
            #pragma unroll
            for (int f = 0; f < 4; ++f) {
                const int ar = wm*64 + f*16 + frow + ((TAPS == 3) ? t : 0);
                const int br = wn*64 + f*16 + frow;
                #pragma unroll
                for (int ks = 0; ks < 2; ++ks) {
                    a[f][ks] = *(const bf16x8*)&As[ar*64 + (((ks*4 + fsl) ^ (ar & 7))*8)];
                    b[f][ks] = *(const bf16x8*)&Ws[(t*128 + br)*64 + (((ks*4 + fsl) ^ (br & 7))*8)];
                }
            }
            #pragma unroll
            for (int fi = 0; fi < 4; ++fi)
                #pragma unroll
                for (int fj = 0; fj < 4; ++fj)
                    #pragma unroll
                    for (int ks = 0; ks < 2; ++ks)
                        acc[fi][fj] = __builtin_amdgcn_mfma_f32_16x16x32_bf16(
                            a[fi][ks], b[fj][ks], acc[fi][fj], 0, 0, 0);
        }
    }

    #pragma unroll
    for (int fi = 0; fi < 4; ++fi) {
        #pragma unroll
        for (int i = 0; i < 4; ++i) {
            const int gm = m0 + wm*64 + fi*16 + (lane >> 4)*4 + i;
            const int bb = gm >> 11;
            #pragma unroll
            for (int fj = 0; fj < 4; ++fj) {
                const int col = n0 + wn*64 + fj*16 + frow;
                float r = acc[fi][fj][i];
                if (EPI == 0) {
                    ((u16*)Cout)[(size_t)gm*N + col] = f2b(r + bias[col]);
                } else if (EPI == 1) {
                    if (bias) r += bias[col];
                    const float g = mod[bb*H6 + gate_off + col];
                    ((float*)Cout)[(size_t)gm*N + col] =
                        prev[(size_t)gm*N + col] + g*r;
                } else if (EPI == 2) {
                    ((u16*)Cout)[(size_t)gm*N + col] = f2b(r);
                } else {
                    const float h = b2f(other[(size_t)gm*N + col]);
                    const float v = h / (1.f + __expf(-h)) * r;
                    ((u16*)Cout)[((size_t)bb*LPAD + 1 + (gm & 2047))*N + col] = f2b(v);
                }
            }
        }
    }
}

// ---------------- RMSNorm + RoPE + split qkv (bf16 in/out; Q pre-scaled) --------
__global__ void rope_rms(const u16* __restrict__ qkv,
                         const float* __restrict__ qn_w, const float* __restrict__ kn_w,
                         const float* __restrict__ fcos, const float* __restrict__ fsin,
                         u16* __restrict__ Q, u16* __restrict__ K, u16* __restrict__ V) {
    int bh = blockIdx.y;
    int l  = blockIdx.x*4 + (threadIdx.x >> 6);
    int d  = threadIdx.x & 63;
    int b  = bh >> 4, h = bh & 15;
    size_t base = ((size_t)(b*Lc + l))*3072 + (size_t)(h*64 + d)*3;
    float qv = b2f(qkv[base + 0]);
    float kv = b2f(qkv[base + 1]);
    float vv = b2f(qkv[base + 2]);
    float qs = wave_reduce_sum(qv*qv) * (1.f/64.f);
    float ks = wave_reduce_sum(kv*kv) * (1.f/64.f);
    float qn = qv * rsqrtf(qs + 1e-6f) * qn_w[d];
    float kn = kv * rsqrtf(ks + 1e-6f) * kn_w[d];
    float c = fcos[l*64 + d], s = fsin[l*64 + d];
    float qp = __shfl_xor(qn, 1, 64);
    float kp = __shfl_xor(kn, 1, 64);
    float qr = (d & 1) ? qp : -qp;
    float kr = (d & 1) ? kp : -kp;
    size_t o = ((size_t)bh*Lc + l)*64 + d;
    Q[o] = f2b((qn*c + qr*s) * 0.125f);     // fold 1/sqrt(D) into Q
    K[o] = f2b(kn*c + kr*s);
    V[o] = f2b(vv);
}

// ---------------- V transpose: [bh][l][64] -> [bh][64][l] ----------------
__global__ void vtrans(const u16* __restrict__ V, u16* __restrict__ Vt) {
    __shared__ u16 t[64][65];
    int bh = blockIdx.y, l0 = blockIdx.x*64;
    int tid = threadIdx.x;
    #pragma unroll
    for (int p = 0; p < 16; ++p) {
        int idx = p*256 + tid; int r = idx >> 6, c = idx & 63;
        t[r][c] = V[((size_t)bh*Lc + l0 + r)*64 + c];
    }
    __syncthreads();
    #pragma unroll
    for (int p = 0; p < 16; ++p) {
        int idx = p*256 + tid; int d = idx >> 6, c = idx & 63;
        Vt[((size_t)bh*64 + d)*Lc + l0 + c] = t[c][d];
    }
}

// ---------------- flash attention v2: 32x32 MFMA, in-register softmax ----------
// grid (Lc/128, B*NH), 256 thr. Wave owns 32 q-rows. S^T = mfma(K,Q) so each
// lane holds P half-rows for q-col (lane&31); cvt_pk+permlane32_swap builds the
// PV A-fragment in-register (no P LDS). Double-buffered K/V, 1 barrier/tile.
#define PV_STEP(c, SV) do {                                                        \
    unsigned cA,cB,cC,cD;                                                          \
    asm("v_cvt_pk_bf16_f32 %0,%1,%2" : "=v"(cA) : "v"(SV[((c)&1)*8+0]), "v"(SV[((c)&1)*8+1])); \
    asm("v_cvt_pk_bf16_f32 %0,%1,%2" : "=v"(cB) : "v"(SV[((c)&1)*8+2]), "v"(SV[((c)&1)*8+3])); \
    asm("v_cvt_pk_bf16_f32 %0,%1,%2" : "=v"(cC) : "v"(SV[((c)&1)*8+4]), "v"(SV[((c)&1)*8+5])); \
    asm("v_cvt_pk_bf16_f32 %0,%1,%2" : "=v"(cD) : "v"(SV[((c)&1)*8+6]), "v"(SV[((c)&1)*8+7])); \
    asm("v_permlane32_swap_b32 %0, %1" : "+v"(cA), "+v"(cC));                      \
    asm("v_permlane32_swap_b32 %0, %1" : "+v"(cB), "+v"(cD));                      \
    union { unsigned u[4]; bf16x8 v; } pa_;                                        \
    pa_.u[0]=cA; pa_.u[1]=cB; pa_.u[2]=cC; pa_.u[3]=cD;                            \
    const int slot_ = (c)*2 + g;                                                   \
    bf16x8 vA = *(const bf16x8*)&Vs[cur][q31*64 + ((slot_ ^ (q31 & 7))*8)];        \
    bf16x8 vB = *(const bf16x8*)&Vs[cur][(32+q31)*64 + ((slot_ ^ (q31 & 7))*8)];   \
    o0 = __builtin_amdgcn_mfma_f32_32x32x16_bf16(pa_.v, vA, o0, 0,0,0);            \
    o1 = __builtin_amdgcn_mfma_f32_32x32x16_bf16(pa_.v, vB, o1, 0,0,0);            \
} while(0)

__global__ __launch_bounds__(256, 2)
void attn_kernel(const u16* __restrict__ Q, const u16* __restrict__ K,
                 const u16* __restrict__ Vt, u16* __restrict__ Opad)
{
    __shared__ u16 Ks[2][4096];
    __shared__ u16 Vs[2][4096];
    __shared__ float lred[4][32];
    const int tid = threadIdx.x;
    const int w = tid >> 6, lane = tid & 63;
    const int q31 = lane & 31, g = lane >> 5;
    const int bh = blockIdx.y;
    const int q0 = blockIdx.x*128 + w*32;
    const u16* Qb = Q  + (size_t)bh*Lc*64;
    const u16* Kb = K  + (size_t)bh*Lc*64;
    const u16* Vb = Vt + (size_t)bh*Lc*64;   // [64 d][2048 kv]

    // Q B-fragment: col q=q0+q31, k-elems d = st*16 + g*8
    bf16x8 qf[4];
    #pragma unroll
    for (int st = 0; st < 4; ++st)
        qf[st] = *(const bf16x8*)&Qb[(size_t)(q0 + q31)*64 + st*16 + g*8];

    f32x16 o0 = {}, o1 = {};
    float m_ = -1e30f, l_ = 0.f;

    const int sr = lane >> 3;
    const int sg = ((lane & 7) ^ sr) * 8;

    // prologue: stage tile 0
    #pragma unroll
    for (int i = 0; i < 2; ++i) {
        const int c = w + i*4;
        async16(&Ks[0][c*512], Kb + (size_t)(c*8 + sr)*64 + sg);
        async16(&Vs[0][c*512], Vb + (size_t)(c*8 + sr)*Lc + sg);
    }
    __syncthreads();

    int cur = 0;
    for (int kv0 = 0; kv0 < Lc; kv0 += 64) {
        if (kv0 + 64 < Lc) {
            #pragma unroll
            for (int i = 0; i < 2; ++i) {
                const int c = w + i*4;
                async16(&Ks[cur^1][c*512], Kb + (size_t)(kv0 + 64 + c*8 + sr)*64 + sg);
                async16(&Vs[cur^1][c*512], Vb + (size_t)(c*8 + sr)*Lc + kv0 + 64 + sg);
            }
        }
        // S^T = K · Q^T  (two 32-kv subtiles)
        f32x16 s0 = {}, s1 = {};
        __builtin_amdgcn_s_setprio(1);
        #pragma unroll
        for (int st = 0; st < 4; ++st) {
            const int slot = st*2 + g;
            bf16x8 ka0 = *(const bf16x8*)&Ks[cur][q31*64 + ((slot ^ (q31 & 7))*8)];
            bf16x8 ka1 = *(const bf16x8*)&Ks[cur][(32+q31)*64 + ((slot ^ (q31 & 7))*8)];
            s0 = __builtin_amdgcn_mfma_f32_32x32x16_bf16(ka0, qf[st], s0, 0,0,0);
            s1 = __builtin_amdgcn_mfma_f32_32x32x16_bf16(ka1, qf[st], s1, 0,0,0);
        }
        __builtin_amdgcn_s_setprio(0);
        // in-register online softmax for q-col = q31
        float pmax = s0[0];
        #pragma unroll
        for (int r = 1; r < 16; ++r) pmax = fmaxf(pmax, s0[r]);
        #pragma unroll
        for (int r = 0; r < 16; ++r) pmax = fmaxf(pmax, s1[r]);
        pmax = fmaxf(pmax, __shfl_xor(pmax, 32, 64));
        if (!__all(pmax <= m_ + 8.f)) {
            const float mn = fmaxf(m_, pmax);
            const float al = __expf(m_ - mn);
            m_ = mn; l_ *= al;
            #pragma unroll
            for (int r = 0; r < 16; ++r) { o0[r] *= al; o1[r] *= al; }
        }
        #pragma unroll
        for (int r = 0; r < 16; ++r) {
            const float p0 = __expf(s0[r] - m_); s0[r] = p0; l_ += p0;
            const float p1 = __expf(s1[r] - m_); s1[r] = p1; l_ += p1;
        }
        // PV: build A-fragments from P in-register, B from Vs
        __builtin_amdgcn_s_setprio(1);
        PV_STEP(0, s0); PV_STEP(1, s0); PV_STEP(2, s1); PV_STEP(3, s1);
        __builtin_amdgcn_s_setprio(0);
        __syncthreads();
        cur ^= 1;
    }

    // finalize: l across the half-pair, broadcast per-wave via LDS
    const float lt = l_ + __shfl_xor(l_, 32, 64);
    if (g == 0) lred[w][q31] = lt;
    __syncthreads();
    const int b = bh >> 4, h = bh & 15;
    #pragma unroll
    for (int r = 0; r < 16; ++r) {
        const int ql = (r & 3) + 8*(r >> 2) + 4*g;
        const float inv = 1.f / lred[w][ql];
        const size_t prow = (size_t)b*LPAD + 1 + (q0 + ql);
        Opad[prow*Hc + h*64 + q31]      = f2b(o0[r]*inv);
        Opad[prow*Hc + h*64 + 32 + q31] = f2b(o1[r]*inv);
    }
}

extern "C" void kernel_launch(void* const* d_in, const int* in_sizes, int n_in,
                              void* d_out, int out_size, void* d_ws, size_t ws_size,
                              hipStream_t stream) {
    const float* x      = (const float*)d_in[0];
    const float* cond   = (const float*)d_in[1];
    const float* fcos   = (const float*)d_in[2];
    const float* fsin   = (const float*)d_in[3];
    const float* mod_w  = (const float*)d_in[4];
    const float* mod_b  = (const float*)d_in[5];
    const float* qkv_w  = (const float*)d_in[6];
    const float* qkv_b  = (const float*)d_in[7];
    const float* qn_w   = (const float*)d_in[8];
    const float* kn_w   = (const float*)d_in[9];
    const float* lin1_w = (const float*)d_in[10];
    const float* lin1_b = (const float*)d_in[11];
    const float* w1     = (const float*)d_in[12];
    const float* w2     = (const float*)d_in[13];
    const float* w3     = (const float*)d_in[14];
    float* out = (float*)d_out;
    char* wsb  = (char*)d_ws;

    float* mod  = (float*)(wsb + 0);                       // 48 KB
    u16* Wslot  = (u16*)(wsb + (1u<<16));                  // <=16.5 MiB, reused
    u16* Breg   = (u16*)(wsb + 18u*1024*1024);             // xn1 -> attn_pad
    u16* Creg   = (u16*)(wsb + 27u*1024*1024);             // qkv -> h1a
    u16* Dreg   = (u16*)(wsb + 52u*1024*1024);             // Q,K,V,Vt -> xn2_pad
    u16* Ereg   = (u16*)(wsb + 86u*1024*1024);             // h1_pad

    u16* xn1  = Breg;
    u16* apad = Breg;
    u16* qkvb = Creg;
    u16* h1a  = Creg;
    u16* Qb = Dreg;
    u16* Kb = Dreg + 4194304;
    u16* Vb = Dreg + 8388608;
    u16* Vt = Dreg + 12582912;
    u16* xn2p = Dreg;
    u16* h1p  = Ereg;

    dim3 blk(256);
    mod_kernel<<<dim3(H6/256, Bc), blk, 0, stream>>>(cond, mod_w, mod_b, mod);
    zero_pads<<<dim3((4*2816 + 255)/256), blk, 0, stream>>>(h1p, 2816);
    ln_mod_kernel<false><<<Mc, blk, 0, stream>>>(x, mod, 0, Hc, xn1);
    cvt_plain<<<dim3((3072*1024/4 + 255)/256), blk, 0, stream>>>(qkv_w, Wslot, 3072*1024);
    conv_gemm<1,0,3072,1024><<<dim3(24,32), blk, 0, stream>>>(
        xn1, Wslot, qkv_b, nullptr, nullptr, nullptr, 0, qkvb);
    zero_pads<<<dim3((4*1024 + 255)/256), blk, 0, stream>>>(apad, 1024);   // xn1 dead now
    rope_rms<<<dim3(Lc/4, 32), blk, 0, stream>>>(qkvb, qn_w, kn_w, fcos, fsin, Qb, Kb, Vb);
    vtrans<<<dim3(32, 32), blk, 0, stream>>>(Vb, Vt);
    attn_kernel<<<dim3(16, 32), blk, 0, stream>>>(Qb, Kb, Vt, apad);
    cvt_conv<<<dim3((1024*1024 + 255)/256), blk, 0, stream>>>(lin1_w, Wslot, 1024*1024);
    conv_gemm<3,1,1024,1024><<<dim3(8,32), blk, 0, stream>>>(
        apad, Wslot, lin1_b, x, nullptr, mod, 2*Hc, (void*)out);
    zero_pads<<<dim3((4*1024 + 255)/256), blk, 0, stream>>>(xn2p, 1024);   // Q..Vt dead now
    ln_mod_kernel<true><<<Mc, blk, 0, stream>>>(out, mod, 3*Hc, 4*Hc, xn2p);
    cvt_conv<<<dim3((2816*1024 + 255)/256), blk, 0, stream>>>(w1, Wslot, 2816*1024);
    conv_gemm<3,2,2816,1024><<<dim3(22,32), blk, 0, stream>>>(
        xn2p, Wslot, nullptr, nullptr, nullptr, nullptr, 0, h1a);
    cvt_conv<<<dim3((2816*1024 + 255)/256), blk, 0, stream>>>(w3, Wslot, 2816*1024);
    conv_gemm<3,3,2816,1024><<<dim3(22,32), blk, 0, stream>>>(
        xn2p, Wslot, nullptr, nullptr, h1a, nullptr, 0, h1p);
    cvt_conv<<<dim3((1024*2816 + 255)/256), blk, 0, stream>>>(w2, Wslot, 1024*2816);
    conv_gemm<3,1,1024,2816><<<dim3(8,32), blk, 0, stream>>>(
        h1p, Wslot, nullptr, out, nullptr, mod, 5*Hc, (void*)out);
    (void)in_sizes; (void)n_in; (void)out_size; (void)ws_size;
}